// Round 5
// baseline (162.976 us; speedup 1.0000x reference)
//
#include <hip/hip_runtime.h>
#include <math.h>

#define N_NODES 50000
#define N_EDGES 800000
#define HID     128
#define N_ACT   64
#define N_GRAPH 512
#define N6      (N_NODES * 6)

// bucketing config
#define NWF   2048                 // nodes per dst-window
#define LOGW  11
#define WF    25                   // ceil(50000/2048)
#define CAP   40960                // bucket capacity (mean 32768, sigma ~177)
#define CB    4                    // sub-chunks per window in feat pass
#define EPB   2048                 // edges per place-block
#define PB    ((N_EDGES + EPB - 1) / EPB)

// node-stage config
#define NBLK    512                // nodes per k_node_f block
#define MAXSPAN 16                 // max graphs spanned by one block (LDS path)

// ws layout (float-sized slots); cursor|gsum|cnt contiguous for single memset
#define F_BUCKET 0                          // WF*CAP ints
#define F_CURSOR (F_BUCKET + WF * CAP)      // 32 ints
#define F_GSUM   (F_CURSOR + 32)            // N_GRAPH*HID
#define F_CNT    (F_GSUM + N_GRAPH * HID)   // N_GRAPH
#define F_DINV   (F_CNT + N_GRAPH)          // N_NODES
#define F_XSPAD  (F_DINV + N_NODES)         // N_NODES*8
#define F_SPART  (F_XSPAD + N_NODES * 8)    // CB*N6
#define F_TOTAL  (F_SPART + CB * N6)
#define NEED_BYTES ((size_t)F_TOTAL * 4)
#define ZERO_BYTES ((size_t)(32 + N_GRAPH * HID + N_GRAPH) * 4)

// ===================== fast path =====================

__global__ __launch_bounds__(256) void k_place(const int* __restrict__ ei,
                                               int* __restrict__ bucket,
                                               int* __restrict__ cursor) {
    __shared__ int lc[WF], lb[WF];
    if (threadIdx.x < WF) lc[threadIdx.x] = 0;
    __syncthreads();
    int e0 = blockIdx.x * EPB;
    int pk[8], wl[8];
#pragma unroll
    for (int i = 0; i < 8; ++i) {
        int e = e0 + i * 256 + threadIdx.x;
        wl[i] = -1;
        if (e < N_EDGES) {
            int src = ei[e], dst = ei[N_EDGES + e];
            int w = dst >> LOGW;
            int lp = atomicAdd(&lc[w], 1);          // local slot within (block, window)
            pk[i] = ((dst - (w << LOGW)) << 16) | src;
            wl[i] = (w << 16) | lp;
        }
    }
    __syncthreads();
    if (threadIdx.x < WF)
        lb[threadIdx.x] = atomicAdd(&cursor[threadIdx.x], lc[threadIdx.x]);
    __syncthreads();
#pragma unroll
    for (int i = 0; i < 8; ++i) {
        if (wl[i] >= 0) {
            int w = wl[i] >> 16, lp = wl[i] & 0xffff;
            int pos = lb[w] + lp;
            if (pos < CAP) bucket[w * CAP + pos] = pk[i];
        }
    }
}

// fused degree + scale: block (w,c) owns nodes [w*2048 + c*512, +512).
// Scans window w's bucket once, histograms its quarter, then dinv + xs_pad.
__global__ __launch_bounds__(256) void k_degscale(const int* __restrict__ bucket,
                                                  const int* __restrict__ cursor,
                                                  const float* __restrict__ x,
                                                  float* __restrict__ dinv,
                                                  float* __restrict__ xs_pad) {
    __shared__ float hist[512];
    int w = blockIdx.x, c = blockIdx.y;
    int t = threadIdx.x;
    hist[t] = 0.0f; hist[t + 256] = 0.0f;
    __syncthreads();
    int cw = min(cursor[w], CAP);
    const int* bp = bucket + w * CAP;
    unsigned lo = c * 512u;
    for (int e = t; e < cw; e += 256) {
        unsigned v = (((unsigned)bp[e]) >> 16) - lo;
        if (v < 512u) atomicAdd(&hist[v], 1.0f);
    }
    __syncthreads();
    int n = w * NWF + (int)lo + 2 * t;          // even; handles n, n+1
    if (n < N_NODES) {                           // N_NODES even -> n+1 also valid
        const float4* xp = (const float4*)(x + (size_t)n * 6);
        float4 xa = xp[0], xb = xp[1], xc = xp[2];
        float dv0 = rsqrtf(1.0f + hist[2 * t]);
        float dv1 = rsqrtf(1.0f + hist[2 * t + 1]);
        dinv[n] = dv0;
        dinv[n + 1] = dv1;
        float4 o0 = make_float4(xa.x * dv0, xa.y * dv0, xa.z * dv0, xa.w * dv0);
        float4 o1 = make_float4(xb.x * dv0, xb.y * dv0, 0.0f, 0.0f);
        float4 o2 = make_float4(xb.z * dv1, xb.w * dv1, xc.x * dv1, xc.y * dv1);
        float4 o3 = make_float4(xc.z * dv1, xc.w * dv1, 0.0f, 0.0f);
        float4* op = (float4*)(xs_pad + (size_t)n * 8);
        op[0] = o0; op[1] = o1; op[2] = o2; op[3] = o3;
    }
}

__global__ __launch_bounds__(256) void k_feat_b(const int* __restrict__ bucket,
                                                const int* __restrict__ cursor,
                                                const float* __restrict__ xs_pad,
                                                float* __restrict__ s_part) {
    __shared__ float h[NWF * 6];
    int w = blockIdx.x, c = blockIdx.y;
    float4* h4 = (float4*)h;
    for (int i = threadIdx.x; i < NWF * 6 / 4; i += 256) h4[i] = make_float4(0, 0, 0, 0);
    __syncthreads();
    int cw = min(cursor[w], CAP);
    const int* bp = bucket + w * CAP;
    for (int e = c * 256 + threadIdx.x; e < cw; e += CB * 256) {
        int p = bp[e];
        int u = ((unsigned)p) >> 16;
        int src = p & 0xffff;
        const float4* xp = (const float4*)(xs_pad + (size_t)src * 8);
        float4 a = xp[0], b = xp[1];
        float* hp = &h[u * 6];
        atomicAdd(hp + 0, a.x); atomicAdd(hp + 1, a.y); atomicAdd(hp + 2, a.z);
        atomicAdd(hp + 3, a.w); atomicAdd(hp + 4, b.x); atomicAdd(hp + 5, b.y);
    }
    __syncthreads();
    int gb = w * NWF * 6;
    int lim = min(NWF * 6, N6 - gb);      // multiple of 4
    float4* sp4 = (float4*)(s_part + (size_t)c * N6 + gb);
    for (int i = threadIdx.x; i < lim / 4; i += 256) sp4[i] = h4[i];
}

// block: NBLK nodes; partial-reduce into LDS, W1+ReLU, per-graph LDS rows,
// flush interior graphs with plain stores, boundary graphs with atomics.
__global__ __launch_bounds__(256) void k_node_f(const float* __restrict__ s_part,
                                                const float* __restrict__ xs_pad,
                                                const float* __restrict__ dinv,
                                                const int* __restrict__ batch,
                                                const float* __restrict__ w1,
                                                const float* __restrict__ b1,
                                                float* __restrict__ gsum,
                                                float* __restrict__ cnt) {
    __shared__ float sb[NBLK * 6];
    __shared__ float dvb[NBLK];
    __shared__ int   btb[NBLK];
    __shared__ float gacc[MAXSPAN][HID];
    __shared__ float gcnt[MAXSPAN];
    __shared__ int   sbnd[2];

    int nb0 = blockIdx.x * NBLK;
    int nEnd = min(nb0 + NBLK, N_NODES);
    int nCnt = nEnd - nb0;
    int lim = nCnt * 6;                       // multiple of 4 (nCnt even)

    // phase A: partial reduce into sb (float4)
    {
        float4* sb4 = (float4*)sb;
        int nv = lim >> 2;
        int g4base = (nb0 * 6) >> 2;          // nb0*6 divisible by 4
        for (int i = threadIdx.x; i < nv; i += 256) {
            float4 v = make_float4(0, 0, 0, 0);
#pragma unroll
            for (int c = 0; c < CB; ++c) {
                float4 p = ((const float4*)(s_part + (size_t)c * N6))[g4base + i];
                v.x += p.x; v.y += p.y; v.z += p.z; v.w += p.w;
            }
            sb4[i] = v;
        }
    }
    for (int i = threadIdx.x; i < nCnt; i += 256) {
        dvb[i] = dinv[nb0 + i];
        btb[i] = batch[nb0 + i];
    }
    if (threadIdx.x == 0) {
        sbnd[0] = (nb0 > 0) ? batch[nb0 - 1] : -1;
        sbnd[1] = (nEnd < N_NODES) ? batch[nEnd] : -1;
    }
    for (int i = threadIdx.x; i < MAXSPAN * HID; i += 256) ((float*)gacc)[i] = 0.0f;
    if (threadIdx.x < MAXSPAN) gcnt[threadIdx.x] = 0.0f;
    __syncthreads();

    // phase B: add self-loop term (vectorized: 2 float4 per node)
    for (int i = threadIdx.x; i < nCnt; i += 256) {
        const float4* xp = (const float4*)(xs_pad + (size_t)(nb0 + i) * 8);
        float4 a = xp[0], b = xp[1];
        float* sp = &sb[i * 6];
        sp[0] += a.x; sp[1] += a.y; sp[2] += a.z;
        sp[3] += a.w; sp[4] += b.x; sp[5] += b.y;
    }
    __syncthreads();

    // phase C: compute + accumulate
    int f = threadIdx.x & (HID - 1);
    int sub = threadIdx.x >> 7;
    float w1r[6];
#pragma unroll
    for (int k = 0; k < 6; ++k) w1r[k] = w1[k * HID + f];
    float b1f = b1[f];

    int bfirst = btb[0];
    int blast = btb[nCnt - 1];
    int span = blast - bfirst + 1;
    int bprev = sbnd[0], bnext = sbnd[1];
    int i0 = sub * (NBLK / 2);
    int i1 = min(i0 + (NBLK / 2), nCnt);

    if (span <= MAXSPAN) {
        float acc = 0.0f, rc = 0.0f;
        int curb = -1;
        for (int i = i0; i < i1; ++i) {
            const float* sp = &sb[i * 6];
            float t = 0.0f;
#pragma unroll
            for (int k = 0; k < 6; ++k) t = fmaf(sp[k], w1r[k], t);
            float a = fmaxf(fmaf(dvb[i], t, b1f), 0.0f);
            int b = btb[i];
            if (b != curb) {
                if (curb >= 0) {
                    atomicAdd(&gacc[curb - bfirst][f], acc);
                    if (f == 0) atomicAdd(&gcnt[curb - bfirst], rc);
                }
                acc = 0.0f; rc = 0.0f; curb = b;
            }
            acc += a; rc += 1.0f;
        }
        if (curb >= 0) {
            atomicAdd(&gacc[curb - bfirst][f], acc);
            if (f == 0) atomicAdd(&gcnt[curb - bfirst], rc);
        }
        __syncthreads();
        for (int idx = threadIdx.x; idx < span * HID; idx += 256) {
            int r = idx >> 7, ff = idx & (HID - 1);
            int gid = bfirst + r;
            float v = gacc[r][ff];
            if (gid == bprev || gid == bnext) atomicAdd(&gsum[gid * HID + ff], v);
            else gsum[gid * HID + ff] = v;
        }
        if (threadIdx.x < span) {
            int gid = bfirst + threadIdx.x;
            float v = gcnt[threadIdx.x];
            if (gid == bprev || gid == bnext) atomicAdd(&cnt[gid], v);
            else cnt[gid] = v;
        }
    } else {
        // safety fallback: direct global atomics per run
        float acc = 0.0f, rc = 0.0f;
        int curb = -1;
        for (int i = i0; i < i1; ++i) {
            const float* sp = &sb[i * 6];
            float t = 0.0f;
#pragma unroll
            for (int k = 0; k < 6; ++k) t = fmaf(sp[k], w1r[k], t);
            float a = fmaxf(fmaf(dvb[i], t, b1f), 0.0f);
            int b = btb[i];
            if (b != curb) {
                if (curb >= 0) {
                    atomicAdd(&gsum[curb * HID + f], acc);
                    if (f == 0) atomicAdd(&cnt[curb], rc);
                }
                acc = 0.0f; rc = 0.0f; curb = b;
            }
            acc += a; rc += 1.0f;
        }
        if (curb >= 0) {
            atomicAdd(&gsum[curb * HID + f], acc);
            if (f == 0) atomicAdd(&cnt[curb], rc);
        }
    }
}

__global__ __launch_bounds__(128) void k_head(const float* __restrict__ gsum,
                                              const float* __restrict__ cnt,
                                              const float* __restrict__ wl,
                                              const float* __restrict__ bl,
                                              const float* __restrict__ w2,
                                              const float* __restrict__ b2,
                                              float* __restrict__ out) {
    __shared__ float sg[HID];
    __shared__ float sg2[HID];
    int g = blockIdx.x;
    int t = threadIdx.x;

    float ic = 1.0f / fmaxf(cnt[g], 1.0f);
    sg[t] = gsum[g * HID + t] * ic;
    __syncthreads();

    float acc = bl[t];
    for (int k = 0; k < HID; ++k) acc = fmaf(sg[k], wl[k * HID + t], acc);
    sg2[t] = fmaxf(acc, 0.0f);
    __syncthreads();

    if (t < N_ACT) {
        float l = b2[t];
        for (int f = 0; f < HID; ++f) l = fmaf(sg2[f], w2[f * N_ACT + t], l);
        float m = l;
#pragma unroll
        for (int off = 32; off > 0; off >>= 1) m = fmaxf(m, __shfl_xor(m, off));
        float e = expf(l - m);
        float ssum = e;
#pragma unroll
        for (int off = 32; off > 0; off >>= 1) ssum += __shfl_xor(ssum, off);
        out[g * N_ACT + t] = l - m - logf(ssum);
    }
}

// ===================== fallback path (round-1, known-correct) =====================

__global__ void k_init(float* __restrict__ deg, float* __restrict__ gsum,
                       float* __restrict__ cnt) {
    int i = blockIdx.x * blockDim.x + threadIdx.x;
    if (i < N_NODES) deg[i] = 1.0f;
    if (i < N_GRAPH * HID) gsum[i] = 0.0f;
    if (i < N_GRAPH) cnt[i] = 0.0f;
}

__global__ void k_deg(const int* __restrict__ ei, float* __restrict__ deg) {
    int e = blockIdx.x * blockDim.x + threadIdx.x;
    if (e < N_EDGES) atomicAdd(&deg[ei[N_EDGES + e]], 1.0f);
}

__global__ void k_scale(const float* __restrict__ x, const int* __restrict__ batch,
                        const float* __restrict__ deg, float* __restrict__ dinv,
                        float* __restrict__ xs, float* __restrict__ s,
                        float* __restrict__ cnt) {
    int n = blockIdx.x * blockDim.x + threadIdx.x;
    if (n >= N_NODES) return;
    float dv = rsqrtf(deg[n]);
    dinv[n] = dv;
#pragma unroll
    for (int k = 0; k < 6; ++k) {
        float v = x[n * 6 + k] * dv;
        xs[n * 6 + k] = v;
        s[n * 6 + k] = v;
    }
    atomicAdd(&cnt[batch[n]], 1.0f);
}

__global__ void k_scatter(const int* __restrict__ ei, const float* __restrict__ xs,
                          float* __restrict__ s) {
    int e = blockIdx.x * blockDim.x + threadIdx.x;
    if (e >= N_EDGES) return;
    int src = ei[e];
    int dst = ei[N_EDGES + e];
#pragma unroll
    for (int k = 0; k < 6; ++k)
        atomicAdd(&s[dst * 6 + k], xs[src * 6 + k]);
}

__global__ __launch_bounds__(256) void k_node(const float* __restrict__ s,
                                              const float* __restrict__ dinv,
                                              const int* __restrict__ batch,
                                              const float* __restrict__ w1,
                                              const float* __restrict__ b1,
                                              float* __restrict__ gsum) {
    int f = threadIdx.x & (HID - 1);
    int sub = threadIdx.x >> 7;
    int base = blockIdx.x * 16 + sub * 8;
    float w1r[6];
#pragma unroll
    for (int k = 0; k < 6; ++k) w1r[k] = w1[k * HID + f];
    float b1f = b1[f];
    float acc = 0.0f;
    int curb = -1;
    for (int i = 0; i < 8; ++i) {
        int n = base + i;
        if (n >= N_NODES) break;
        float t = 0.0f;
#pragma unroll
        for (int k = 0; k < 6; ++k) t = fmaf(s[n * 6 + k], w1r[k], t);
        float a = fmaxf(fmaf(dinv[n], t, b1f), 0.0f);
        int b = batch[n];
        if (b != curb) {
            if (curb >= 0) atomicAdd(&gsum[curb * HID + f], acc);
            acc = 0.0f;
            curb = b;
        }
        acc += a;
    }
    if (curb >= 0) atomicAdd(&gsum[curb * HID + f], acc);
}

// ===================== launch =====================

extern "C" void kernel_launch(void* const* d_in, const int* in_sizes, int n_in,
                              void* d_out, int out_size, void* d_ws, size_t ws_size,
                              hipStream_t stream) {
    const float* x     = (const float*)d_in[0];
    const int*   ei    = (const int*)d_in[1];
    const int*   batch = (const int*)d_in[2];
    const float* w1    = (const float*)d_in[3];
    const float* b1    = (const float*)d_in[4];
    const float* wl    = (const float*)d_in[5];
    const float* bl    = (const float*)d_in[6];
    const float* w2    = (const float*)d_in[7];
    const float* b2    = (const float*)d_in[8];
    float* out = (float*)d_out;
    float* ws = (float*)d_ws;

    if (ws_size >= NEED_BYTES) {
        int*   bucket = (int*)(ws + F_BUCKET);
        int*   cursor = (int*)(ws + F_CURSOR);
        float* gsum   = ws + F_GSUM;
        float* cnt    = ws + F_CNT;
        float* dinv   = ws + F_DINV;
        float* xs_pad = ws + F_XSPAD;
        float* s_part = ws + F_SPART;

        hipMemsetAsync(cursor, 0, ZERO_BYTES, stream);   // cursor|gsum|cnt
        k_place<<<PB, 256, 0, stream>>>(ei, bucket, cursor);
        k_degscale<<<dim3(WF, 4), 256, 0, stream>>>(bucket, cursor, x, dinv, xs_pad);
        k_feat_b<<<dim3(WF, CB), 256, 0, stream>>>(bucket, cursor, xs_pad, s_part);
        k_node_f<<<(N_NODES + NBLK - 1) / NBLK, 256, 0, stream>>>(s_part, xs_pad, dinv, batch, w1, b1, gsum, cnt);
        k_head<<<N_GRAPH, 128, 0, stream>>>(gsum, cnt, wl, bl, w2, b2, out);
    } else {
        float* deg  = ws;
        float* dinv = deg + N_NODES;
        float* xs   = dinv + N_NODES;
        float* s    = xs + N6;
        float* gsum = s + N6;
        float* cnt  = gsum + N_GRAPH * HID;

        k_init<<<(N_GRAPH * HID + 255) / 256, 256, 0, stream>>>(deg, gsum, cnt);
        k_deg<<<(N_EDGES + 255) / 256, 256, 0, stream>>>(ei, deg);
        k_scale<<<(N_NODES + 255) / 256, 256, 0, stream>>>(x, batch, deg, dinv, xs, s, cnt);
        k_scatter<<<(N_EDGES + 255) / 256, 256, 0, stream>>>(ei, xs, s);
        k_node<<<(N_NODES + 15) / 16, 256, 0, stream>>>(s, dinv, batch, w1, b1, gsum);
        k_head<<<N_GRAPH, 128, 0, stream>>>(gsum, cnt, wl, bl, w2, b2, out);
    }
}

// Round 6
// 101.863 us; speedup vs baseline: 1.6000x; 1.6000x over previous
//
#include <hip/hip_runtime.h>
#include <math.h>

#define N_NODES 50000
#define N_EDGES 800000
#define HID     128
#define N_ACT   64
#define N_GRAPH 512
#define N6      (N_NODES * 6)

// bucketing config
#define NWF   2048                 // nodes per dst-window
#define LOGW  11
#define WF    25                   // ceil(50000/2048)
#define CAP   40960                // bucket capacity (mean 32768, sigma ~177)
#define CB    16                   // feat sub-chunks per window (4 iters @512t)
#define DC    16                   // deg sub-chunks per window (4 iters @512t)
#define EPB   1024                 // edges per place-block
#define PB    ((N_EDGES + EPB - 1) / EPB)

// node-stage config
#define NBLK    256                // nodes per k_node_f block
#define MAXSPAN 16                 // max graphs spanned by one block (LDS path)

// ws layout (float-sized slots); cursor|gsum|cnt contiguous for single memset
#define F_BUCKET 0                          // WF*CAP ints
#define F_CURSOR (F_BUCKET + WF * CAP)      // 32 ints
#define F_GSUM   (F_CURSOR + 32)            // N_GRAPH*HID
#define F_CNT    (F_GSUM + N_GRAPH * HID)   // N_GRAPH
#define F_DINV   (F_CNT + N_GRAPH)          // N_NODES
#define F_XSPAD  (F_DINV + N_NODES)         // N_NODES*8
#define F_DEGP   (F_XSPAD + N_NODES * 8)    // DC*N_NODES
#define F_SPART  (F_DEGP + DC * N_NODES)    // CB*N6
#define F_TOTAL  (F_SPART + CB * N6)
#define NEED_BYTES ((size_t)F_TOTAL * 4)
#define ZERO_BYTES ((size_t)(32 + N_GRAPH * HID + N_GRAPH) * 4)

// ===================== fast path =====================

__global__ __launch_bounds__(256) void k_place(const int* __restrict__ ei,
                                               int* __restrict__ bucket,
                                               int* __restrict__ cursor) {
    __shared__ int lc[WF], lb[WF];
    if (threadIdx.x < WF) lc[threadIdx.x] = 0;
    __syncthreads();
    int e0 = blockIdx.x * EPB;
    int pk[4], wl[4];
#pragma unroll
    for (int i = 0; i < 4; ++i) {
        int e = e0 + i * 256 + threadIdx.x;
        wl[i] = -1;
        if (e < N_EDGES) {
            int src = ei[e], dst = ei[N_EDGES + e];
            int w = dst >> LOGW;
            int lp = atomicAdd(&lc[w], 1);          // local slot within (block, window)
            pk[i] = ((dst - (w << LOGW)) << 16) | src;
            wl[i] = (w << 16) | lp;
        }
    }
    __syncthreads();
    if (threadIdx.x < WF)
        lb[threadIdx.x] = atomicAdd(&cursor[threadIdx.x], lc[threadIdx.x]);
    __syncthreads();
#pragma unroll
    for (int i = 0; i < 4; ++i) {
        if (wl[i] >= 0) {
            int w = wl[i] >> 16, lp = wl[i] & 0xffff;
            int pos = lb[w] + lp;
            if (pos < CAP) bucket[w * CAP + pos] = pk[i];
        }
    }
}

// degree partials: block (w,c) scans 1/DC of window w's bucket (4 batched
// iters @ 512t), histograms the full 2048-node window in LDS, writes partial.
__global__ __launch_bounds__(512) void k_degp(const int* __restrict__ bucket,
                                              const int* __restrict__ cursor,
                                              float* __restrict__ degp) {
    __shared__ float hist[NWF];
    int w = blockIdx.x, c = blockIdx.y;
    int t = threadIdx.x;
    for (int i = t; i < NWF; i += 512) hist[i] = 0.0f;
    __syncthreads();
    int cw = min(cursor[w], CAP);
    const int* bp = bucket + w * CAP;
    const int stride = DC * 512;
    int e = c * 512 + t;
    for (; e + 3 * stride < cw; e += 4 * stride) {
        int p0 = bp[e], p1 = bp[e + stride], p2 = bp[e + 2 * stride], p3 = bp[e + 3 * stride];
        atomicAdd(&hist[((unsigned)p0) >> 16], 1.0f);
        atomicAdd(&hist[((unsigned)p1) >> 16], 1.0f);
        atomicAdd(&hist[((unsigned)p2) >> 16], 1.0f);
        atomicAdd(&hist[((unsigned)p3) >> 16], 1.0f);
    }
    for (; e < cw; e += stride) atomicAdd(&hist[((unsigned)bp[e]) >> 16], 1.0f);
    __syncthreads();
    int nb = w * NWF;
    int lim = min(NWF, N_NODES - nb);
    for (int i = t; i < lim; i += 512) degp[c * N_NODES + nb + i] = hist[i];
}

// reduce DC degree partials -> dinv, xs_pad (2 nodes/thread, float4-aligned x)
__global__ __launch_bounds__(256) void k_scale2(const float* __restrict__ degp,
                                                const float* __restrict__ x,
                                                float* __restrict__ dinv,
                                                float* __restrict__ xs_pad) {
    int n = blockIdx.x * 512 + 2 * threadIdx.x;
    if (n >= N_NODES) return;                 // N_NODES even -> n+1 also valid
    float d0 = 1.0f, d1 = 1.0f;               // self-loop
#pragma unroll
    for (int c = 0; c < DC; ++c) {
        d0 += degp[c * N_NODES + n];
        d1 += degp[c * N_NODES + n + 1];
    }
    float dv0 = rsqrtf(d0), dv1 = rsqrtf(d1);
    dinv[n] = dv0; dinv[n + 1] = dv1;
    const float4* xp = (const float4*)(x + (size_t)n * 6);
    float4 xa = xp[0], xb = xp[1], xc = xp[2];
    float4* op = (float4*)(xs_pad + (size_t)n * 8);
    op[0] = make_float4(xa.x * dv0, xa.y * dv0, xa.z * dv0, xa.w * dv0);
    op[1] = make_float4(xb.x * dv0, xb.y * dv0, 0.0f, 0.0f);
    op[2] = make_float4(xb.z * dv1, xb.w * dv1, xc.x * dv1, xc.y * dv1);
    op[3] = make_float4(xc.z * dv1, xc.w * dv1, 0.0f, 0.0f);
}

// feature scatter: block (w,c) scans 1/CB of window w's bucket (4 batched
// iters @ 512t, all gathers issued before atomics), LDS-accumulates, flushes.
__global__ __launch_bounds__(512) void k_feat(const int* __restrict__ bucket,
                                              const int* __restrict__ cursor,
                                              const float* __restrict__ xs_pad,
                                              float* __restrict__ s_part) {
    __shared__ float h[NWF * 6];
    int w = blockIdx.x, c = blockIdx.y;
    int t = threadIdx.x;
    float4* h4 = (float4*)h;
    for (int i = t; i < NWF * 6 / 4; i += 512) h4[i] = make_float4(0, 0, 0, 0);
    __syncthreads();
    int cw = min(cursor[w], CAP);
    const int* bp = bucket + w * CAP;
    const int stride = CB * 512;
    int e = c * 512 + t;
    for (; e + 3 * stride < cw; e += 4 * stride) {
        int p0 = bp[e], p1 = bp[e + stride], p2 = bp[e + 2 * stride], p3 = bp[e + 3 * stride];
        const float4* q0 = (const float4*)(xs_pad + (size_t)(p0 & 0xffff) * 8);
        const float4* q1 = (const float4*)(xs_pad + (size_t)(p1 & 0xffff) * 8);
        const float4* q2 = (const float4*)(xs_pad + (size_t)(p2 & 0xffff) * 8);
        const float4* q3 = (const float4*)(xs_pad + (size_t)(p3 & 0xffff) * 8);
        float4 a0 = q0[0], b0 = q0[1];
        float4 a1 = q1[0], b1 = q1[1];
        float4 a2 = q2[0], b2 = q2[1];
        float4 a3 = q3[0], b3 = q3[1];
        float* hp;
        hp = &h[(((unsigned)p0) >> 16) * 6];
        atomicAdd(hp + 0, a0.x); atomicAdd(hp + 1, a0.y); atomicAdd(hp + 2, a0.z);
        atomicAdd(hp + 3, a0.w); atomicAdd(hp + 4, b0.x); atomicAdd(hp + 5, b0.y);
        hp = &h[(((unsigned)p1) >> 16) * 6];
        atomicAdd(hp + 0, a1.x); atomicAdd(hp + 1, a1.y); atomicAdd(hp + 2, a1.z);
        atomicAdd(hp + 3, a1.w); atomicAdd(hp + 4, b1.x); atomicAdd(hp + 5, b1.y);
        hp = &h[(((unsigned)p2) >> 16) * 6];
        atomicAdd(hp + 0, a2.x); atomicAdd(hp + 1, a2.y); atomicAdd(hp + 2, a2.z);
        atomicAdd(hp + 3, a2.w); atomicAdd(hp + 4, b2.x); atomicAdd(hp + 5, b2.y);
        hp = &h[(((unsigned)p3) >> 16) * 6];
        atomicAdd(hp + 0, a3.x); atomicAdd(hp + 1, a3.y); atomicAdd(hp + 2, a3.z);
        atomicAdd(hp + 3, a3.w); atomicAdd(hp + 4, b3.x); atomicAdd(hp + 5, b3.y);
    }
    for (; e < cw; e += stride) {
        int p = bp[e];
        const float4* q = (const float4*)(xs_pad + (size_t)(p & 0xffff) * 8);
        float4 a = q[0], b = q[1];
        float* hp = &h[(((unsigned)p) >> 16) * 6];
        atomicAdd(hp + 0, a.x); atomicAdd(hp + 1, a.y); atomicAdd(hp + 2, a.z);
        atomicAdd(hp + 3, a.w); atomicAdd(hp + 4, b.x); atomicAdd(hp + 5, b.y);
    }
    __syncthreads();
    int gb = w * NWF * 6;
    int lim = min(NWF * 6, N6 - gb);      // multiple of 4
    float4* sp4 = (float4*)(s_part + (size_t)c * N6 + gb);
    for (int i = t; i < lim / 4; i += 512) sp4[i] = h4[i];
}

// block: NBLK nodes; partial-reduce into LDS, W1+ReLU, per-graph LDS rows,
// flush interior graphs with plain stores, boundary graphs with atomics.
__global__ __launch_bounds__(256) void k_node_f(const float* __restrict__ s_part,
                                                const float* __restrict__ xs_pad,
                                                const float* __restrict__ dinv,
                                                const int* __restrict__ batch,
                                                const float* __restrict__ w1,
                                                const float* __restrict__ b1,
                                                float* __restrict__ gsum,
                                                float* __restrict__ cnt) {
    __shared__ float sb[NBLK * 6];
    __shared__ float dvb[NBLK];
    __shared__ int   btb[NBLK];
    __shared__ float gacc[MAXSPAN][HID];
    __shared__ float gcnt[MAXSPAN];
    __shared__ int   sbnd[2];

    int nb0 = blockIdx.x * NBLK;
    int nEnd = min(nb0 + NBLK, N_NODES);
    int nCnt = nEnd - nb0;
    int lim = nCnt * 6;                       // multiple of 4 (nCnt even)

    // phase A: partial reduce into sb (float4)
    {
        float4* sb4 = (float4*)sb;
        int nv = lim >> 2;
        int g4base = (nb0 * 6) >> 2;          // nb0*6 divisible by 4
        for (int i = threadIdx.x; i < nv; i += 256) {
            float4 v = make_float4(0, 0, 0, 0);
#pragma unroll
            for (int c = 0; c < CB; ++c) {
                float4 p = ((const float4*)(s_part + (size_t)c * N6))[g4base + i];
                v.x += p.x; v.y += p.y; v.z += p.z; v.w += p.w;
            }
            sb4[i] = v;
        }
    }
    for (int i = threadIdx.x; i < nCnt; i += 256) {
        dvb[i] = dinv[nb0 + i];
        btb[i] = batch[nb0 + i];
    }
    if (threadIdx.x == 0) {
        sbnd[0] = (nb0 > 0) ? batch[nb0 - 1] : -1;
        sbnd[1] = (nEnd < N_NODES) ? batch[nEnd] : -1;
    }
    for (int i = threadIdx.x; i < MAXSPAN * HID; i += 256) ((float*)gacc)[i] = 0.0f;
    if (threadIdx.x < MAXSPAN) gcnt[threadIdx.x] = 0.0f;
    __syncthreads();

    // phase B: add self-loop term (vectorized: 2 float4 per node)
    for (int i = threadIdx.x; i < nCnt; i += 256) {
        const float4* xp = (const float4*)(xs_pad + (size_t)(nb0 + i) * 8);
        float4 a = xp[0], b = xp[1];
        float* sp = &sb[i * 6];
        sp[0] += a.x; sp[1] += a.y; sp[2] += a.z;
        sp[3] += a.w; sp[4] += b.x; sp[5] += b.y;
    }
    __syncthreads();

    // phase C: compute + accumulate
    int f = threadIdx.x & (HID - 1);
    int sub = threadIdx.x >> 7;
    float w1r[6];
#pragma unroll
    for (int k = 0; k < 6; ++k) w1r[k] = w1[k * HID + f];
    float b1f = b1[f];

    int bfirst = btb[0];
    int blast = btb[nCnt - 1];
    int span = blast - bfirst + 1;
    int bprev = sbnd[0], bnext = sbnd[1];
    int i0 = sub * (NBLK / 2);
    int i1 = min(i0 + (NBLK / 2), nCnt);

    if (span <= MAXSPAN) {
        float acc = 0.0f, rc = 0.0f;
        int curb = -1;
        for (int i = i0; i < i1; ++i) {
            const float* sp = &sb[i * 6];
            float t = 0.0f;
#pragma unroll
            for (int k = 0; k < 6; ++k) t = fmaf(sp[k], w1r[k], t);
            float a = fmaxf(fmaf(dvb[i], t, b1f), 0.0f);
            int b = btb[i];
            if (b != curb) {
                if (curb >= 0) {
                    atomicAdd(&gacc[curb - bfirst][f], acc);
                    if (f == 0) atomicAdd(&gcnt[curb - bfirst], rc);
                }
                acc = 0.0f; rc = 0.0f; curb = b;
            }
            acc += a; rc += 1.0f;
        }
        if (curb >= 0) {
            atomicAdd(&gacc[curb - bfirst][f], acc);
            if (f == 0) atomicAdd(&gcnt[curb - bfirst], rc);
        }
        __syncthreads();
        for (int idx = threadIdx.x; idx < span * HID; idx += 256) {
            int r = idx >> 7, ff = idx & (HID - 1);
            int gid = bfirst + r;
            float v = gacc[r][ff];
            if (gid == bprev || gid == bnext) atomicAdd(&gsum[gid * HID + ff], v);
            else gsum[gid * HID + ff] = v;
        }
        if (threadIdx.x < span) {
            int gid = bfirst + threadIdx.x;
            float v = gcnt[threadIdx.x];
            if (gid == bprev || gid == bnext) atomicAdd(&cnt[gid], v);
            else cnt[gid] = v;
        }
    } else {
        // safety fallback: direct global atomics per run
        float acc = 0.0f, rc = 0.0f;
        int curb = -1;
        for (int i = i0; i < i1; ++i) {
            const float* sp = &sb[i * 6];
            float t = 0.0f;
#pragma unroll
            for (int k = 0; k < 6; ++k) t = fmaf(sp[k], w1r[k], t);
            float a = fmaxf(fmaf(dvb[i], t, b1f), 0.0f);
            int b = btb[i];
            if (b != curb) {
                if (curb >= 0) {
                    atomicAdd(&gsum[curb * HID + f], acc);
                    if (f == 0) atomicAdd(&cnt[curb], rc);
                }
                acc = 0.0f; rc = 0.0f; curb = b;
            }
            acc += a; rc += 1.0f;
        }
        if (curb >= 0) {
            atomicAdd(&gsum[curb * HID + f], acc);
            if (f == 0) atomicAdd(&cnt[curb], rc);
        }
    }
}

__global__ __launch_bounds__(128) void k_head(const float* __restrict__ gsum,
                                              const float* __restrict__ cnt,
                                              const float* __restrict__ wl,
                                              const float* __restrict__ bl,
                                              const float* __restrict__ w2,
                                              const float* __restrict__ b2,
                                              float* __restrict__ out) {
    __shared__ float sg[HID];
    __shared__ float sg2[HID];
    int g = blockIdx.x;
    int t = threadIdx.x;

    float ic = 1.0f / fmaxf(cnt[g], 1.0f);
    sg[t] = gsum[g * HID + t] * ic;
    __syncthreads();

    float acc = bl[t];
    for (int k = 0; k < HID; ++k) acc = fmaf(sg[k], wl[k * HID + t], acc);
    sg2[t] = fmaxf(acc, 0.0f);
    __syncthreads();

    if (t < N_ACT) {
        float l = b2[t];
        for (int f = 0; f < HID; ++f) l = fmaf(sg2[f], w2[f * N_ACT + t], l);
        float m = l;
#pragma unroll
        for (int off = 32; off > 0; off >>= 1) m = fmaxf(m, __shfl_xor(m, off));
        float e = expf(l - m);
        float ssum = e;
#pragma unroll
        for (int off = 32; off > 0; off >>= 1) ssum += __shfl_xor(ssum, off);
        out[g * N_ACT + t] = l - m - logf(ssum);
    }
}

// ===================== fallback path (round-1, known-correct) =====================

__global__ void k_init(float* __restrict__ deg, float* __restrict__ gsum,
                       float* __restrict__ cnt) {
    int i = blockIdx.x * blockDim.x + threadIdx.x;
    if (i < N_NODES) deg[i] = 1.0f;
    if (i < N_GRAPH * HID) gsum[i] = 0.0f;
    if (i < N_GRAPH) cnt[i] = 0.0f;
}

__global__ void k_deg(const int* __restrict__ ei, float* __restrict__ deg) {
    int e = blockIdx.x * blockDim.x + threadIdx.x;
    if (e < N_EDGES) atomicAdd(&deg[ei[N_EDGES + e]], 1.0f);
}

__global__ void k_scale(const float* __restrict__ x, const int* __restrict__ batch,
                        const float* __restrict__ deg, float* __restrict__ dinv,
                        float* __restrict__ xs, float* __restrict__ s,
                        float* __restrict__ cnt) {
    int n = blockIdx.x * blockDim.x + threadIdx.x;
    if (n >= N_NODES) return;
    float dv = rsqrtf(deg[n]);
    dinv[n] = dv;
#pragma unroll
    for (int k = 0; k < 6; ++k) {
        float v = x[n * 6 + k] * dv;
        xs[n * 6 + k] = v;
        s[n * 6 + k] = v;
    }
    atomicAdd(&cnt[batch[n]], 1.0f);
}

__global__ void k_scatter(const int* __restrict__ ei, const float* __restrict__ xs,
                          float* __restrict__ s) {
    int e = blockIdx.x * blockDim.x + threadIdx.x;
    if (e >= N_EDGES) return;
    int src = ei[e];
    int dst = ei[N_EDGES + e];
#pragma unroll
    for (int k = 0; k < 6; ++k)
        atomicAdd(&s[dst * 6 + k], xs[src * 6 + k]);
}

__global__ __launch_bounds__(256) void k_node(const float* __restrict__ s,
                                              const float* __restrict__ dinv,
                                              const int* __restrict__ batch,
                                              const float* __restrict__ w1,
                                              const float* __restrict__ b1,
                                              float* __restrict__ gsum) {
    int f = threadIdx.x & (HID - 1);
    int sub = threadIdx.x >> 7;
    int base = blockIdx.x * 16 + sub * 8;
    float w1r[6];
#pragma unroll
    for (int k = 0; k < 6; ++k) w1r[k] = w1[k * HID + f];
    float b1f = b1[f];
    float acc = 0.0f;
    int curb = -1;
    for (int i = 0; i < 8; ++i) {
        int n = base + i;
        if (n >= N_NODES) break;
        float t = 0.0f;
#pragma unroll
        for (int k = 0; k < 6; ++k) t = fmaf(s[n * 6 + k], w1r[k], t);
        float a = fmaxf(fmaf(dinv[n], t, b1f), 0.0f);
        int b = batch[n];
        if (b != curb) {
            if (curb >= 0) atomicAdd(&gsum[curb * HID + f], acc);
            acc = 0.0f;
            curb = b;
        }
        acc += a;
    }
    if (curb >= 0) atomicAdd(&gsum[curb * HID + f], acc);
}

// ===================== launch =====================

extern "C" void kernel_launch(void* const* d_in, const int* in_sizes, int n_in,
                              void* d_out, int out_size, void* d_ws, size_t ws_size,
                              hipStream_t stream) {
    const float* x     = (const float*)d_in[0];
    const int*   ei    = (const int*)d_in[1];
    const int*   batch = (const int*)d_in[2];
    const float* w1    = (const float*)d_in[3];
    const float* b1    = (const float*)d_in[4];
    const float* wl    = (const float*)d_in[5];
    const float* bl    = (const float*)d_in[6];
    const float* w2    = (const float*)d_in[7];
    const float* b2    = (const float*)d_in[8];
    float* out = (float*)d_out;
    float* ws = (float*)d_ws;

    if (ws_size >= NEED_BYTES) {
        int*   bucket = (int*)(ws + F_BUCKET);
        int*   cursor = (int*)(ws + F_CURSOR);
        float* gsum   = ws + F_GSUM;
        float* cnt    = ws + F_CNT;
        float* dinv   = ws + F_DINV;
        float* xs_pad = ws + F_XSPAD;
        float* degp   = ws + F_DEGP;
        float* s_part = ws + F_SPART;

        hipMemsetAsync(cursor, 0, ZERO_BYTES, stream);   // cursor|gsum|cnt
        k_place<<<PB, 256, 0, stream>>>(ei, bucket, cursor);
        k_degp<<<dim3(WF, DC), 512, 0, stream>>>(bucket, cursor, degp);
        k_scale2<<<(N_NODES + 511) / 512, 256, 0, stream>>>(degp, x, dinv, xs_pad);
        k_feat<<<dim3(WF, CB), 512, 0, stream>>>(bucket, cursor, xs_pad, s_part);
        k_node_f<<<(N_NODES + NBLK - 1) / NBLK, 256, 0, stream>>>(s_part, xs_pad, dinv, batch, w1, b1, gsum, cnt);
        k_head<<<N_GRAPH, 128, 0, stream>>>(gsum, cnt, wl, bl, w2, b2, out);
    } else {
        float* deg  = ws;
        float* dinv = deg + N_NODES;
        float* xs   = dinv + N_NODES;
        float* s    = xs + N6;
        float* gsum = s + N6;
        float* cnt  = gsum + N_GRAPH * HID;

        k_init<<<(N_GRAPH * HID + 255) / 256, 256, 0, stream>>>(deg, gsum, cnt);
        k_deg<<<(N_EDGES + 255) / 256, 256, 0, stream>>>(ei, deg);
        k_scale<<<(N_NODES + 255) / 256, 256, 0, stream>>>(x, batch, deg, dinv, xs, s, cnt);
        k_scatter<<<(N_EDGES + 255) / 256, 256, 0, stream>>>(ei, xs, s);
        k_node<<<(N_NODES + 15) / 16, 256, 0, stream>>>(s, dinv, batch, w1, b1, gsum);
        k_head<<<N_GRAPH, 128, 0, stream>>>(gsum, cnt, wl, bl, w2, b2, out);
    }
}